// Round 2
// 674.748 us; speedup vs baseline: 1.0306x; 1.0306x over previous
//
#include <hip/hip_runtime.h>

#define B_ 4
#define C_ 128
#define H_ 256
#define W_ 256

static constexpr int    BC    = B_ * C_;                     // 512 planes
static constexpr size_t PLANE = (size_t)H_ * W_;             // 65536
static constexpr size_t NTOT  = (size_t)B_ * C_ * H_ * W_;   // 33,554,432

typedef float f4 __attribute__((ext_vector_type(4)));

// ---------------------------------------------------------------------------
// One fused kernel. grid = 2048 blocks of 256 threads.
//   bid & 3 : role (0=down, 1=up, 2=right, 3=left)
//   bid >> 2: plane p = b*C + c   (roles of the same plane are ADJACENT in
//             dispatch order -> plane read once from HBM, 3x from L2/L3)
// All output stores are nontemporal so the 512 MiB write stream does not
// evict the input planes from cache before the sibling roles re-read them.
//
// Vertical roles: thread = column, serial chain over H with an 8-deep
// register double buffer: loads for group i+1 are issued BEFORE the chain
// and stores of group i, so the vmcnt wait for the next data never waits on
// store completion, and 8 loads/wave (2 KB) stay in flight.
//
// Horizontal roles: thread = row (256 rows == 256 threads, every lane owns a
// full-W chain). W is processed in 16 chunks of 16 cols:
//   issue global loads (chunk+1) -> scan chunk from LDS -> barrier ->
//   flush chunk (coalesced f4 nt stores) -> write staged regs to LDS -> barrier
// xs/os use stride 17 => scan reads/writes are 2-way-per-bank (free).
// ---------------------------------------------------------------------------
__global__ __launch_bounds__(256) void irnn_fused(
    const float* __restrict__ x,
    const float* __restrict__ w_up,    const float* __restrict__ b_up,
    const float* __restrict__ w_right, const float* __restrict__ b_right,
    const float* __restrict__ w_down,  const float* __restrict__ b_down,
    const float* __restrict__ w_left,  const float* __restrict__ b_left,
    float* __restrict__ out_up,   float* __restrict__ out_right,
    float* __restrict__ out_down, float* __restrict__ out_left)
{
    __shared__ float xs[256][17];   // 17,408 B  (input chunk, scan order)
    __shared__ float os[256][17];   // 17,408 B  (output chunk staging)

    const int bid  = blockIdx.x;
    const int role = bid & 3;
    const int p    = bid >> 2;              // 0..511
    const int c    = p & (C_ - 1);
    const int tid  = threadIdx.x;

    if (role < 2) {
        // ================= vertical (down / up) =================
        const bool  dn  = (role == 0);
        const float wc  = dn ? w_down[c] : w_up[c];
        const float bb  = dn ? b_down[c] : b_up[c];
        float* const o  = dn ? out_down : out_up;
        const ptrdiff_t stp = dn ? (ptrdiff_t)W_ : -(ptrdiff_t)W_;
        const size_t start = p * PLANE + (size_t)tid
                           + (dn ? (size_t)0 : (size_t)(H_ - 1) * W_);
        const float* xp = x + start;
        float*       op = o + start;

        // boundary row: out = x (no weight/bias/relu)
        float prev = *xp;
        __builtin_nontemporal_store(prev, op);
        xp += stp; op += stp;

        // 255 remaining rows = 30*8 + 8 + 7, software-pipelined
        float cur[8], nxt[8], tail[7];
        #pragma unroll
        for (int j = 0; j < 8; ++j) cur[j] = xp[j * stp];
        const float* xq = xp + 8 * stp;

        for (int g = 0; g < 30; ++g) {
            #pragma unroll
            for (int j = 0; j < 8; ++j) nxt[j] = xq[j * stp];   // prefetch
            #pragma unroll
            for (int j = 0; j < 8; ++j) {
                prev = fmaxf(fmaf(wc, prev, bb + cur[j]), 0.f);
                __builtin_nontemporal_store(prev, op + j * stp);
            }
            op += 8 * stp;
            #pragma unroll
            for (int j = 0; j < 8; ++j) cur[j] = nxt[j];
            xq += 8 * stp;
        }
        #pragma unroll
        for (int j = 0; j < 7; ++j) tail[j] = xq[j * stp];      // prefetch tail
        #pragma unroll
        for (int j = 0; j < 8; ++j) {                           // rows 241..248
            prev = fmaxf(fmaf(wc, prev, bb + cur[j]), 0.f);
            __builtin_nontemporal_store(prev, op + j * stp);
        }
        op += 8 * stp;
        #pragma unroll
        for (int j = 0; j < 7; ++j) {                           // rows 249..255
            prev = fmaxf(fmaf(wc, prev, bb + tail[j]), 0.f);
            __builtin_nontemporal_store(prev, op + j * stp);
        }
    } else {
        // ================= horizontal (right / left) =================
        const bool  rt  = (role == 2);
        const float wc  = rt ? w_right[c] : w_left[c];
        const float bb  = rt ? b_right[c] : b_left[c];
        float* const       opl = (rt ? out_right : out_left) + p * PLANE;
        const float* const xpl = x + p * PLANE;

        f4 stage[4];   // reg-staged global loads for the NEXT chunk

        // ---- prologue: load + stage chunk 0
        #pragma unroll
        for (int k = 0; k < 4; ++k) {
            const int i = tid + (k << 8);
            const int r = i >> 2;
            const int q = i & 3;
            const int cb = rt ? (4 * q) : (252 - 4 * q);
            stage[k] = *(const f4*)(xpl + (size_t)r * W_ + cb);
        }
        #pragma unroll
        for (int k = 0; k < 4; ++k) {
            const int i = tid + (k << 8);
            const int r = i >> 2;
            const int q = i & 3;
            #pragma unroll
            for (int j = 0; j < 4; ++j) {
                const int sl = rt ? (4 * q + j) : (4 * q + 3 - j);
                xs[r][sl] = stage[k][j];            // store in SCAN order
            }
        }
        __syncthreads();

        float prev = 0.f;
        for (int ch = 0; ch < 16; ++ch) {
            if (ch < 15) {
                // ---- issue global loads for chunk ch+1 (overlap HBM latency)
                #pragma unroll
                for (int k = 0; k < 4; ++k) {
                    const int i = tid + (k << 8);
                    const int r = i >> 2;
                    const int q = i & 3;
                    const int cb = rt ? ((ch + 1) * 16 + 4 * q)
                                      : (252 - (ch + 1) * 16 - 4 * q);
                    stage[k] = *(const f4*)(xpl + (size_t)r * W_ + cb);
                }
            }

            // ---- scan 16 steps: thread t owns row t
            float vals[16];
            #pragma unroll
            for (int j = 0; j < 16; ++j) vals[j] = xs[tid][j];
            #pragma unroll
            for (int j = 0; j < 16; ++j) {
                float v = fmaxf(fmaf(wc, prev, bb + vals[j]), 0.f);
                if (ch == 0 && j == 0) v = vals[0]; // boundary col = input
                os[tid][j] = v;
                prev = v;
            }
            __syncthreads();

            // ---- flush chunk: coalesced f4 nontemporal stores
            #pragma unroll
            for (int k = 0; k < 4; ++k) {
                const int i = tid + (k << 8);
                const int r = i >> 2;
                const int q = i & 3;
                f4 v;
                #pragma unroll
                for (int j = 0; j < 4; ++j) {
                    const int sl = rt ? (4 * q + j) : (4 * q + 3 - j);
                    v[j] = os[r][sl];
                }
                const int cb = rt ? (ch * 16 + 4 * q) : (252 - ch * 16 - 4 * q);
                __builtin_nontemporal_store(v, (f4*)(opl + (size_t)r * W_ + cb));
            }
            if (ch < 15) {
                // ---- stage regs -> LDS for next chunk (scan order)
                #pragma unroll
                for (int k = 0; k < 4; ++k) {
                    const int i = tid + (k << 8);
                    const int r = i >> 2;
                    const int q = i & 3;
                    #pragma unroll
                    for (int j = 0; j < 4; ++j) {
                        const int sl = rt ? (4 * q + j) : (4 * q + 3 - j);
                        xs[r][sl] = stage[k][j];
                    }
                }
            }
            __syncthreads();
        }
    }
}

// ---------------------------------------------------------------------------
extern "C" void kernel_launch(void* const* d_in, const int* in_sizes, int n_in,
                              void* d_out, int out_size, void* d_ws, size_t ws_size,
                              hipStream_t stream) {
    // setup_inputs() dict order: input, w_up, b_up, w_right, b_right,
    //                            w_down, b_down, w_left, b_left
    const float* x       = (const float*)d_in[0];
    const float* w_up    = (const float*)d_in[1];
    const float* b_up    = (const float*)d_in[2];
    const float* w_right = (const float*)d_in[3];
    const float* b_right = (const float*)d_in[4];
    const float* w_down  = (const float*)d_in[5];
    const float* b_down  = (const float*)d_in[6];
    const float* w_left  = (const float*)d_in[7];
    const float* b_left  = (const float*)d_in[8];

    float* out       = (float*)d_out;       // [up | right | down | left]
    float* out_up    = out;
    float* out_right = out + NTOT;
    float* out_down  = out + 2 * NTOT;
    float* out_left  = out + 3 * NTOT;

    irnn_fused<<<dim3(4 * BC), dim3(256), 0, stream>>>(
        x, w_up, b_up, w_right, b_right, w_down, b_down, w_left, b_left,
        out_up, out_right, out_down, out_left);
}

// Round 3
// 646.325 us; speedup vs baseline: 1.0759x; 1.0440x over previous
//
#include <hip/hip_runtime.h>

#define B_ 4
#define C_ 128
#define H_ 256
#define W_ 256

static constexpr int    BC    = B_ * C_;                     // 512 planes
static constexpr size_t PLANE = (size_t)H_ * W_;             // 65536
static constexpr size_t NTOT  = (size_t)B_ * C_ * H_ * W_;   // 33,554,432
static constexpr ptrdiff_t PW = (ptrdiff_t)W_;

typedef float f4 __attribute__((ext_vector_type(4)));

// ---------------------------------------------------------------------------
// grid = 1536 blocks of 256 threads; plane p = bid/3, sub = bid%3:
//   sub 0: vertical block (down + up chains interleaved, thread = column)
//   sub 1: horizontal block rows 0..127   (right + left fused)
//   sub 2: horizontal block rows 128..255 (right + left fused)
// Same-plane blocks are adjacent in dispatch so x planes are read from HBM
// once and re-read from L3. ALL output stores are nontemporal and cover full
// 128-B lines per wave instruction (no partial-line nt writes anywhere).
//
// Vertical: dual chains (down from row 0, up from row 255) in one pass —
// 16 loads in flight per thread (4 KB/wave) and 2x ILP on the dependent
// FMA chain.
//
// Horizontal: 128 rows/block; tid<128 scans right for row tid, tid>=128
// scans left for row tid-128. W processed in 8 chunks of 32 cols:
//   top of loop: issue next chunk's global loads into regs (latency hidden
//     under scan + barrier + flush)
//   scan in LDS IN PLACE (row stride 67 -> 2-way bank aliasing, free)
//   barrier; flush (full-line f4 nt stores) + same-thread reg->LDS staging
//   barrier.
// LDS 34,304 B -> 4 blocks/CU -> 16 waves/CU.
// ---------------------------------------------------------------------------
__global__ __launch_bounds__(256, 4) void irnn_fused(
    const float* __restrict__ x,
    const float* __restrict__ w_up,    const float* __restrict__ b_up,
    const float* __restrict__ w_right, const float* __restrict__ b_right,
    const float* __restrict__ w_down,  const float* __restrict__ b_down,
    const float* __restrict__ w_left,  const float* __restrict__ b_left,
    float* __restrict__ out_up,   float* __restrict__ out_right,
    float* __restrict__ out_down, float* __restrict__ out_left)
{
    __shared__ float xs[128][67];      // 34,304 B; slots 0..31 right, 33..64 left

    const int bid = blockIdx.x;
    const int p   = bid / 3;                 // plane 0..511
    const int sub = bid - 3 * p;             // 0,1,2
    const int c   = p & (C_ - 1);
    const int tid = threadIdx.x;
    const size_t pbase = (size_t)p * PLANE;

    if (sub == 0) {
        // ================= vertical: down + up in one pass =================
        const float wd = w_down[c], bd = b_down[c];
        const float wu = w_up[c],   bu = b_up[c];
        const float* xb = x + pbase + tid;
        float* od = out_down + pbase + tid;
        float* ou = out_up   + pbase + tid;

        // boundary rows: out = x
        float pd = xb[0];
        float pu = xb[255 * PW];
        __builtin_nontemporal_store(pd, od);
        __builtin_nontemporal_store(pu, ou + 255 * PW);

        const float* xd = xb + PW;           // down input: row 1 ascending
        const float* xu = xb + 254 * PW;     // up   input: row 254 descending
        float* sd = od + PW;
        float* su = ou + 254 * PW;

        float cd[8], cu[8], nd[8], nu[8];
        #pragma unroll
        for (int j = 0; j < 8; ++j) { cd[j] = xd[j * PW]; cu[j] = xu[-j * PW]; }
        xd += 8 * PW; xu -= 8 * PW;

        for (int g = 0; g < 30; ++g) {
            #pragma unroll
            for (int j = 0; j < 8; ++j) { nd[j] = xd[j * PW]; nu[j] = xu[-j * PW]; }
            #pragma unroll
            for (int j = 0; j < 8; ++j) {
                pd = fmaxf(fmaf(wd, pd, bd + cd[j]), 0.f);
                pu = fmaxf(fmaf(wu, pu, bu + cu[j]), 0.f);
                __builtin_nontemporal_store(pd, sd + j * PW);
                __builtin_nontemporal_store(pu, su - j * PW);
            }
            sd += 8 * PW; su -= 8 * PW;
            xd += 8 * PW; xu -= 8 * PW;
            #pragma unroll
            for (int j = 0; j < 8; ++j) { cd[j] = nd[j]; cu[j] = nu[j]; }
        }
        // tail: 8 rows from cd/cu (241..248 / 14..7), then 7 (249..255 / 6..0)
        float td[7], tu[7];
        #pragma unroll
        for (int j = 0; j < 7; ++j) { td[j] = xd[j * PW]; tu[j] = xu[-j * PW]; }
        #pragma unroll
        for (int j = 0; j < 8; ++j) {
            pd = fmaxf(fmaf(wd, pd, bd + cd[j]), 0.f);
            pu = fmaxf(fmaf(wu, pu, bu + cu[j]), 0.f);
            __builtin_nontemporal_store(pd, sd + j * PW);
            __builtin_nontemporal_store(pu, su - j * PW);
        }
        sd += 8 * PW; su -= 8 * PW;
        #pragma unroll
        for (int j = 0; j < 7; ++j) {
            pd = fmaxf(fmaf(wd, pd, bd + td[j]), 0.f);
            pu = fmaxf(fmaf(wu, pu, bu + tu[j]), 0.f);
            __builtin_nontemporal_store(pd, sd + j * PW);
            __builtin_nontemporal_store(pu, su - j * PW);
        }
    } else {
        // ================= horizontal: right + left in one block ===========
        const int r0  = (sub - 1) << 7;      // 0 or 128
        const int d   = tid >> 7;            // 0 = right scanner, 1 = left
        const int rr  = tid & 127;           // scan row within stripe
        const float wc = d ? w_left[c] : w_right[c];
        const float bb = d ? b_left[c] : b_right[c];
        const float* xpl = x + pbase + (size_t)r0 * W_;
        float* o_r = out_right + pbase + (size_t)r0 * W_;
        float* o_l = out_left  + pbase + (size_t)r0 * W_;

        const int q    = tid & 7;            // f4 slot within 32-col chunk
        const int rbas = tid >> 3;           // 0..31

        f4 sreg[8];
        // ---- prologue: load + stage chunk 0 (both directions)
        #pragma unroll
        for (int k = 0; k < 8; ++k) {
            const int df  = k >> 2;                       // 0 right, 1 left
            const int rrr = rbas + ((k & 3) << 5);        // 0..127
            const int cb  = df ? (224 + 4 * q) : (4 * q);
            sreg[k] = *(const f4*)(xpl + (size_t)rrr * W_ + cb);
        }
        #pragma unroll
        for (int k = 0; k < 8; ++k) {
            const int df  = k >> 2;
            const int rrr = rbas + ((k & 3) << 5);
            #pragma unroll
            for (int j = 0; j < 4; ++j) {
                const int sl = df ? (64 - 4 * q - j) : (4 * q + j); // scan order
                xs[rrr][sl] = sreg[k][j];
            }
        }
        __syncthreads();

        float prev = 0.f;
        float* xrow = &xs[rr][d ? 33 : 0];

        for (int ch = 0; ch < 8; ++ch) {
            if (ch < 7) {
                // ---- issue chunk ch+1 global loads (hidden under scan+flush)
                #pragma unroll
                for (int k = 0; k < 8; ++k) {
                    const int df  = k >> 2;
                    const int rrr = rbas + ((k & 3) << 5);
                    const int cb  = df ? (224 - 32 * (ch + 1) + 4 * q)
                                       : (32 * (ch + 1) + 4 * q);
                    sreg[k] = *(const f4*)(xpl + (size_t)rrr * W_ + cb);
                }
            }

            // ---- scan 32 steps in place (thread owns its row+direction)
            float vals[32];
            #pragma unroll
            for (int j = 0; j < 32; ++j) vals[j] = xrow[j];
            #pragma unroll
            for (int j = 0; j < 32; ++j) {
                float v = fmaxf(fmaf(wc, prev, bb + vals[j]), 0.f);
                if (j == 0 && ch == 0) v = vals[0];   // boundary col = input
                xrow[j] = v;
                prev = v;
            }
            __syncthreads();   // scan results visible; all input reads done

            // ---- flush (full-line nt stores) + same-thread restage
            #pragma unroll
            for (int k = 0; k < 8; ++k) {
                const int df  = k >> 2;
                const int rrr = rbas + ((k & 3) << 5);
                f4 v;
                #pragma unroll
                for (int j = 0; j < 4; ++j) {
                    const int sl = df ? (64 - 4 * q - j) : (4 * q + j);
                    v[j] = xs[rrr][sl];
                }
                const int cb = df ? (224 - 32 * ch + 4 * q) : (32 * ch + 4 * q);
                float* dst = (df ? o_l : o_r) + (size_t)rrr * W_ + cb;
                __builtin_nontemporal_store(v, (f4*)dst);
                if (ch < 7) {
                    #pragma unroll
                    for (int j = 0; j < 4; ++j) {
                        const int sl = df ? (64 - 4 * q - j) : (4 * q + j);
                        xs[rrr][sl] = sreg[k][j];     // same slots this thread
                    }                                 // just flushed -> no race
                }
            }
            __syncthreads();   // staged chunk visible to scanners
        }
    }
}

// ---------------------------------------------------------------------------
extern "C" void kernel_launch(void* const* d_in, const int* in_sizes, int n_in,
                              void* d_out, int out_size, void* d_ws, size_t ws_size,
                              hipStream_t stream) {
    // setup_inputs() dict order: input, w_up, b_up, w_right, b_right,
    //                            w_down, b_down, w_left, b_left
    const float* x       = (const float*)d_in[0];
    const float* w_up    = (const float*)d_in[1];
    const float* b_up    = (const float*)d_in[2];
    const float* w_right = (const float*)d_in[3];
    const float* b_right = (const float*)d_in[4];
    const float* w_down  = (const float*)d_in[5];
    const float* b_down  = (const float*)d_in[6];
    const float* w_left  = (const float*)d_in[7];
    const float* b_left  = (const float*)d_in[8];

    float* out       = (float*)d_out;       // [up | right | down | left]
    float* out_up    = out;
    float* out_right = out + NTOT;
    float* out_down  = out + 2 * NTOT;
    float* out_left  = out + 3 * NTOT;

    irnn_fused<<<dim3(3 * BC), dim3(256), 0, stream>>>(
        x, w_up, b_up, w_right, b_right, w_down, b_down, w_left, b_left,
        out_up, out_right, out_down, out_left);
}